// Round 1
// 239.258 us; speedup vs baseline: 1.0268x; 1.0268x over previous
//
#include <hip/hip_runtime.h>

#define CH 256
#define HH 128
#define WW 128
#define HW (HH * WW)
#define SEGH 16   // rows per vertical segment
#define NSEG 8    // 128 / SEGH

__device__ __forceinline__ float rdlane(float v, int l) {
    return __int_as_float(__builtin_amdgcn_readlane(__float_as_int(v), l));
}
__device__ __forceinline__ float uni(float v) {
    return __int_as_float(__builtin_amdgcn_readfirstlane(__float_as_int(v)));
}

// One block per (b,c) image. 1024 threads (16 waves).
// Dynamic LDS: 64 KiB result plane + 8 KiB segment scratch = 72 KiB (2 blocks/CU).
//
//   Params:  lane-split transcendentals (lanes 0-11, one each), broadcast via
//            v_readlane -> SGPRs. No 12-deep serial expf/tanhf per thread.
//   Phase H  (pre-barrier): cold float4 row read, constant-decay Kogge-Stone
//            row scans, writes m0*lr + m1*rl to LDS plane.
//   Phase V1 (pre-barrier): thread=(col,seg); loads 16-row column chunk into
//            REGISTERS xv[16] (kept live across the barrier -- no re-read),
//            computes segment exit states b2/b3, writes to scratch.
//   --- one __syncthreads ---
//   Fixup:   compose incoming states Sin/Tin from <=7 summaries.
//   Phase V2: forward pass folds m2*tb into LDS plane (RMW, same-thread cells);
//            backward pass computes bt from xv[] and stores out.
//            Only xv[16] live -> no 32-float array pressure -> no scratch spill.
__global__ __launch_bounds__(1024, 2) void dscan_kernel(
    const float* __restrict__ x,
    const float* __restrict__ decay_logits,
    const float* __restrict__ mix_logits,
    const float* __restrict__ input_scale,
    float* __restrict__ out)
{
    extern __shared__ float smem[];
    float* __restrict__ xs  = smem;           // 16384 floats: result plane
    float* __restrict__ scr = smem + HW;      // 2048 floats: b2 (1024) + b3 (1024)

    const int img  = blockIdx.x;              // b*256 + c
    const int c    = img & (CH - 1);
    const int tid  = threadIdx.x;
    const int lane = tid & 63;
    const int wv   = tid >> 6;                // 0..15

    // ---- lane-split per-channel params ----
    // lanes 0-3: clamped sigmoid(decay); 4-7: softmax numerators; 8-11: 1+tanh
    float pv = 0.0f;
    {
        const int j = lane & 3;
        const int g = lane >> 2;
        if (g == 0) {
            const float v = decay_logits[j * CH + c];
            pv = fminf(fmaxf(1.0f / (1.0f + expf(-v)), 0.05f), 0.995f);
        } else if (g == 1) {
            const float a0 = mix_logits[0 * CH + c];
            const float a1 = mix_logits[1 * CH + c];
            const float a2 = mix_logits[2 * CH + c];
            const float a3 = mix_logits[3 * CH + c];
            const float mm = fmaxf(fmaxf(a0, a1), fmaxf(a2, a3));
            const float aj = (j == 0) ? a0 : (j == 1) ? a1 : (j == 2) ? a2 : a3;
            pv = expf(aj - mm);
        } else if (g == 2) {
            pv = 1.0f + tanhf(input_scale[j * CH + c]);
        }
    }
    const float d0 = rdlane(pv, 0), d1 = rdlane(pv, 1);
    const float d2 = rdlane(pv, 2), d3 = rdlane(pv, 3);
    const float e0 = rdlane(pv, 4), e1 = rdlane(pv, 5);
    const float e2 = rdlane(pv, 6), e3 = rdlane(pv, 7);
    const float s0 = rdlane(pv, 8), s1 = rdlane(pv, 9);
    const float s2 = rdlane(pv, 10), s3 = rdlane(pv, 11);

    const float einv = uni(1.0f / (e0 + e1 + e2 + e3));
    const float m0 = uni(e0 * einv), m1 = uni(e1 * einv);
    const float m2 = uni(e2 * einv), m3 = uni(e3 * einv);
    const float c0 = uni((1.0f - d0) * s0);   // s = d*s + c*x
    const float c1 = uni((1.0f - d1) * s1);
    const float c2 = uni((1.0f - d2) * s2);
    const float c3 = uni((1.0f - d3) * s3);

    // powers of decay for KS steps: q[k] = d^(4*2^k)
    float q0[5], q1[5];
    q0[0] = uni((d0 * d0) * (d0 * d0));
    q1[0] = uni((d1 * d1) * (d1 * d1));
#pragma unroll
    for (int k = 1; k < 5; ++k) {
        q0[k] = uni(q0[k-1] * q0[k-1]);
        q1[k] = uni(q1[k-1] * q1[k-1]);
    }
    float t2v = d2 * d2; t2v = t2v * t2v; t2v = t2v * t2v; const float d2p16 = uni(t2v * t2v);
    float t3v = d3 * d3; t3v = t3v * t3v; t3v = t3v * t3v; const float d3p16 = uni(t3v * t3v);

    const float* __restrict__ xg = x + (size_t)img * HW;
    float* __restrict__ og = out + (size_t)img * HW;

    // ---- Phase H: cold float4 read, constant-decay KS row scans ----
    {
        const int sl   = lane & 31;       // lane within 32-group
        const int half = lane >> 5;       // which row of the pair
        const int rbase = (wv << 1) + half;

        float4 v[4];
#pragma unroll
        for (int it = 0; it < 4; ++it)
            v[it] = *(const float4*)(xg + ((it << 5) + rbase) * WW + (sl << 2));

#pragma unroll
        for (int it = 0; it < 4; ++it) {
            const int r = (it << 5) + rbase;
            const float4 xv4 = v[it];

            // local inclusive compose over the 4 elements
            float bL = c0 * xv4.x;
            bL = fmaf(d0, bL, c0 * xv4.y);
            bL = fmaf(d0, bL, c0 * xv4.z);
            bL = fmaf(d0, bL, c0 * xv4.w);
            float bR = c1 * xv4.w;
            bR = fmaf(d1, bR, c1 * xv4.z);
            bR = fmaf(d1, bR, c1 * xv4.y);
            bR = fmaf(d1, bR, c1 * xv4.x);

            // constant-decay Kogge-Stone over 32 lanes, both directions
#pragma unroll
            for (int k = 0; k < 5; ++k) {
                const int off = 1 << k;
                const float bU = __shfl_up(bL, (unsigned)off, 32);
                bL = fmaf(q0[k], (sl >= off) ? bU : 0.0f, bL);
                const float bD = __shfl_down(bR, (unsigned)off, 32);
                bR = fmaf(q1[k], (sl < 32 - off) ? bD : 0.0f, bR);
            }
            // exclusive incoming states
            float EL = __shfl_up(bL, 1u, 32);
            if (sl == 0) EL = 0.0f;
            float ER = __shfl_down(bR, 1u, 32);
            if (sl == 31) ER = 0.0f;

            // recompute elementwise (exact)
            const float l0 = fmaf(d0, EL, c0 * xv4.x);
            const float l1 = fmaf(d0, l0, c0 * xv4.y);
            const float l2 = fmaf(d0, l1, c0 * xv4.z);
            const float l3 = fmaf(d0, l2, c0 * xv4.w);
            const float r3 = fmaf(d1, ER, c1 * xv4.w);
            const float r2 = fmaf(d1, r3, c1 * xv4.z);
            const float r1 = fmaf(d1, r2, c1 * xv4.y);
            const float r0 = fmaf(d1, r1, c1 * xv4.x);

            float4 o4;
            o4.x = fmaf(m0, l0, m1 * r0);
            o4.y = fmaf(m0, l1, m1 * r1);
            o4.z = fmaf(m0, l2, m1 * r2);
            o4.w = fmaf(m0, l3, m1 * r3);
            *(float4*)(xs + r * WW + (sl << 2)) = o4;
        }
    }

    // ---- Phase V1: load column chunk to registers, segment summaries ----
    const int col = tid & (WW - 1);       // 0..127
    const int seg = tid >> 7;             // 0..7
    const float* __restrict__ xcol = xg + seg * SEGH * WW + col;

    float xv[SEGH];                       // lives across the barrier (16 VGPRs)
    {
#pragma unroll
        for (int i = 0; i < SEGH; ++i) xv[i] = xcol[i * WW];   // L2-warm

        float b2 = 0.0f;
#pragma unroll
        for (int i = 0; i < SEGH; ++i) b2 = fmaf(d2, b2, c2 * xv[i]);

        float b3 = 0.0f;                  // sum d3^i * xv[i] via backward Horner
#pragma unroll
        for (int i = SEGH - 1; i >= 0; --i) b3 = fmaf(d3, b3, xv[i]);
        b3 *= c3;

        scr[tid]        = b2;
        scr[1024 + tid] = b3;
    }

    __syncthreads();   // the ONE barrier

    // ---- Fixup: incoming states per (col, seg); trip counts wave-uniform ----
    float Sin = 0.0f;
    for (int j = 0; j < seg; ++j)
        Sin = fmaf(d2p16, Sin, scr[j * WW + col]);
    float Tin = 0.0f;
    for (int j = NSEG - 1; j > seg; --j)
        Tin = fmaf(d3p16, Tin, scr[1024 + j * WW + col]);

    // ---- Phase V2: apply vertical scans from registers + fused store ----
    {
        float* __restrict__ pcol = xs + seg * SEGH * WW + col;
        float* __restrict__ ocol = og + seg * SEGH * WW + col;

        // forward: fold m2*tb into the plane (same-thread cells; 2-way bank alias = free)
        float s = Sin;
#pragma unroll
        for (int i = 0; i < SEGH; ++i) {
            s = fmaf(d2, s, c2 * xv[i]);
            pcol[i * WW] = fmaf(m2, s, pcol[i * WW]);
        }
        // backward: bt chain + coalesced store (256 B contiguous per wave-instr)
        float t = Tin;
#pragma unroll
        for (int i = SEGH - 1; i >= 0; --i) {
            t = fmaf(d3, t, c3 * xv[i]);
            ocol[i * WW] = fmaf(m3, t, pcol[i * WW]);
        }
    }
}

extern "C" void kernel_launch(void* const* d_in, const int* in_sizes, int n_in,
                              void* d_out, int out_size, void* d_ws, size_t ws_size,
                              hipStream_t stream) {
    const float* x  = (const float*)d_in[0];
    const float* dl = (const float*)d_in[1];
    const float* ml = (const float*)d_in[2];
    const float* is = (const float*)d_in[3];
    float* out = (float*)d_out;

    const size_t lds_bytes = (size_t)(HW + 2048) * sizeof(float);   // 73728

    static bool attr_set = false;   // idempotent host-side attribute; value never changes
    if (!attr_set) {
        (void)hipFuncSetAttribute((const void*)dscan_kernel,
                                  hipFuncAttributeMaxDynamicSharedMemorySize,
                                  (int)lds_bytes);
        attr_set = true;
    }

    dim3 grid(2048), block(1024);
    hipLaunchKernelGGL(dscan_kernel, grid, block, lds_bytes, stream, x, dl, ml, is, out);
}